// Round 1
// baseline (5691.896 us; speedup 1.0000x reference)
//
#include <hip/hip_runtime.h>
#include <cmath>

#define BB 512
#define CC 128
#define HW 225

// ---------- block reduction helpers (blockDim == 256) ----------
__device__ __forceinline__ float block_reduce_max(float v, float* red, int t) {
  red[t] = v; __syncthreads();
  for (int st = 128; st > 0; st >>= 1) { if (t < st) red[t] = fmaxf(red[t], red[t+st]); __syncthreads(); }
  float r = red[0]; __syncthreads();
  return r;
}
__device__ __forceinline__ float block_reduce_sum(float v, float* red, int t) {
  red[t] = v; __syncthreads();
  for (int st = 128; st > 0; st >>= 1) { if (t < st) red[t] += red[t+st]; __syncthreads(); }
  float r = red[0]; __syncthreads();
  return r;
}

// ---------- BN stats: one block per channel ----------
__global__ __launch_bounds__(256) void k_bnstats(const float* __restrict__ x, int C,
                          const float* __restrict__ g, const float* __restrict__ bt,
                          float* __restrict__ scale, float* __restrict__ shift) {
  int c = blockIdx.x, t = threadIdx.x;
  float s = 0.f, sq = 0.f;
  for (int b = 0; b < BB; ++b) {
    const float* row = x + ((size_t)b*C + c)*HW;
    if (t < HW) { float v = row[t]; s += v; sq += v*v; }
  }
  __shared__ float rs[256], rq[256];
  rs[t] = s; rq[t] = sq; __syncthreads();
  for (int st = 128; st > 0; st >>= 1) { if (t < st) { rs[t]+=rs[t+st]; rq[t]+=rq[t+st]; } __syncthreads(); }
  if (t == 0) {
    const float N = (float)BB*HW;
    float mean = rs[0]/N;
    float var  = rq[0]/N - mean*mean;
    float sc = g[c]*rsqrtf(var + 1e-5f);
    scale[c] = sc; shift[c] = bt[c] - mean*sc;
  }
}

// ---------- attention 1 (concat + center-similarity attention), writes A ----------
__global__ __launch_bounds__(256) void k_attn1(const float* __restrict__ x1, const float* __restrict__ x2,
                        const float* __restrict__ lam, float* __restrict__ A) {
  int b = blockIdx.x, t = threadIdx.x;
  __shared__ float cent[CC];
  __shared__ float red[256];
  const float* xb1 = x1 + (size_t)b*64*HW;
  const float* xb2 = x2 + (size_t)b*64*HW;
  if (t < CC) cent[t] = (t < 64) ? xb1[t*HW + 112] : xb2[(t-64)*HW + 112];
  __syncthreads();
  float e2 = 0.f, dot = 0.f, qn2 = 0.f, cn2 = 0.f;
  if (t < HW) {
    for (int c = 0; c < CC; ++c) {
      float xv = (c < 64) ? xb1[c*HW + t] : xb2[(c-64)*HW + t];
      float ce = cent[c];
      float d = xv - ce;
      e2 += d*d; dot += xv*ce; qn2 += xv*xv; cn2 += ce*ce;
    }
  }
  float sim_e = 0.f, sim_c = 0.f;
  if (t < HW) {
    sim_e = 1.f/(1.f + sqrtf(e2));
    float qn = sqrtf(qn2), cn = sqrtf(cn2);
    sim_c = dot / (fmaxf(cn, 1e-8f) * fmaxf(qn, 1e-8f));
  }
  float m1 = block_reduce_max((t<HW)? sim_e : -1e30f, red, t);
  float e1v = (t<HW)? expf(sim_e - m1) : 0.f;
  float s1 = block_reduce_sum(e1v, red, t);
  float m2 = block_reduce_max((t<HW)? sim_c : -1e30f, red, t);
  float e2v = (t<HW)? expf(sim_c - m2) : 0.f;
  float s2 = block_reduce_sum(e2v, red, t);
  float lmd = 1.f/(1.f + expf(-lam[0]));
  float am = 1.f + lmd*e1v/s1 + (1.f - lmd)*e2v/s2;
  if (t < HW) {
    float* Ab = A + (size_t)b*CC*HW;
    for (int c = 0; c < CC; ++c) {
      float xv = (c < 64) ? xb1[c*HW + t] : xb2[(c-64)*HW + t];
      Ab[c*HW + t] = xv*am;
    }
  }
}

// ---------- fused BN + 1x1 conv (+ optional dw1x1+bias+relu), in-place on A ----------
// MODE 1: leaky -> *dw + db -> relu      MODE 2: leaky only
template<int MODE>
__global__ __launch_bounds__(256) void k_pw(float* __restrict__ A, const float* __restrict__ W,
                     const float* __restrict__ scale, const float* __restrict__ shift,
                     const float* __restrict__ dw, const float* __restrict__ db) {
  int b = blockIdx.x, t = threadIdx.x;
  __shared__ float xin[CC][HW];
  float* Ab = A + (size_t)b*CC*HW;
  for (int c = 0; c < CC; ++c)
    if (t < HW) xin[c][t] = Ab[c*HW + t]*scale[c] + shift[c];
  __syncthreads();
  if (t < HW) {
    for (int cog = 0; cog < CC/16; ++cog) {
      float acc[16];
      #pragma unroll
      for (int j = 0; j < 16; ++j) acc[j] = 0.f;
      for (int ci0 = 0; ci0 < CC; ci0 += 8) {
        float xv[8];
        #pragma unroll
        for (int k = 0; k < 8; ++k) xv[k] = xin[ci0+k][t];
        #pragma unroll
        for (int j = 0; j < 16; ++j) {
          const float* wr = W + (size_t)(cog*16 + j)*CC + ci0;
          #pragma unroll
          for (int k = 0; k < 8; ++k) acc[j] += wr[k]*xv[k];
        }
      }
      #pragma unroll
      for (int j = 0; j < 16; ++j) {
        int co = cog*16 + j;
        float y = acc[j];
        y = (y >= 0.f) ? y : 0.01f*y;
        if (MODE == 1) { y = y*dw[co] + db[co]; y = fmaxf(y, 0.f); }
        Ab[co*HW + t] = y;
      }
    }
  }
}

// ---------- depthwise 3x3 pad1 + bias + relu, in-place ----------
__global__ __launch_bounds__(256) void k_dw3(float* __restrict__ A, const float* __restrict__ w,
                      const float* __restrict__ db) {
  int b = blockIdx.x, t = threadIdx.x;
  __shared__ float xin[CC][HW];
  float* Ab = A + (size_t)b*CC*HW;
  for (int c = 0; c < CC; ++c)
    if (t < HW) xin[c][t] = Ab[c*HW + t];
  __syncthreads();
  if (t < HW) {
    int y = t/15, x = t - y*15;
    for (int c = 0; c < CC; ++c) {
      float acc = db[c];
      #pragma unroll
      for (int ky = 0; ky < 3; ++ky) {
        int iy = y + ky - 1;
        if (iy < 0 || iy >= 15) continue;
        #pragma unroll
        for (int kx = 0; kx < 3; ++kx) {
          int ix = x + kx - 1;
          if (ix < 0 || ix >= 15) continue;
          acc += w[c*9 + ky*3 + kx]*xin[c][iy*15 + ix];
        }
      }
      Ab[c*HW + t] = fmaxf(acc, 0.f);
    }
  }
}

// ---------- attention 2 (K/V proj + center-distance attention + residual), in-place ----------
__global__ __launch_bounds__(256) void k_attn2(float* __restrict__ A, const float* __restrict__ Wqkv) {
  int b = blockIdx.x, t = threadIdx.x;
  __shared__ float xin[CC][HW];
  __shared__ float cent[CC];
  __shared__ float red[256];
  float* Ab = A + (size_t)b*CC*HW;
  for (int c = 0; c < CC; ++c)
    if (t < HW) xin[c][t] = Ab[c*HW + t];
  __syncthreads();
  if (t < CC) {
    const float* wq = Wqkv + (size_t)t*CC;
    float acc = 0.f;
    for (int ci = 0; ci < CC; ++ci) acc += wq[ci]*xin[ci][112];
    cent[t] = acc;
  }
  __syncthreads();
  float e2 = 0.f;
  if (t < HW) {
    const float* Wk = Wqkv + (size_t)CC*CC;
    for (int cog = 0; cog < 8; ++cog) {
      float acc[16];
      #pragma unroll
      for (int j = 0; j < 16; ++j) acc[j] = 0.f;
      for (int ci0 = 0; ci0 < CC; ci0 += 8) {
        float xv[8];
        #pragma unroll
        for (int k = 0; k < 8; ++k) xv[k] = xin[ci0+k][t];
        #pragma unroll
        for (int j = 0; j < 16; ++j) {
          const float* wr = Wk + (size_t)(cog*16 + j)*CC + ci0;
          #pragma unroll
          for (int k = 0; k < 8; ++k) acc[j] += wr[k]*xv[k];
        }
      }
      #pragma unroll
      for (int j = 0; j < 16; ++j) { float d = cent[cog*16 + j] - acc[j]; e2 += d*d; }
    }
  }
  float sim = (t < HW) ? 1.f/(1.f + sqrtf(e2)) : 0.f;
  float m = block_reduce_max((t<HW)? sim : -1e30f, red, t);
  float ev = (t<HW)? expf(sim - m) : 0.f;
  float s = block_reduce_sum(ev, red, t);
  float att = ev/s;
  if (t < HW) {
    const float* Wv = Wqkv + (size_t)2*CC*CC;
    for (int cog = 0; cog < 8; ++cog) {
      float acc[16];
      #pragma unroll
      for (int j = 0; j < 16; ++j) acc[j] = 0.f;
      for (int ci0 = 0; ci0 < CC; ci0 += 8) {
        float xv[8];
        #pragma unroll
        for (int k = 0; k < 8; ++k) xv[k] = xin[ci0+k][t];
        #pragma unroll
        for (int j = 0; j < 16; ++j) {
          const float* wr = Wv + (size_t)(cog*16 + j)*CC + ci0;
          #pragma unroll
          for (int k = 0; k < 8; ++k) acc[j] += wr[k]*xv[k];
        }
      }
      #pragma unroll
      for (int j = 0; j < 16; ++j) {
        int co = cog*16 + j;
        Ab[co*HW + t] = att*acc[j] + xin[co][t];
      }
    }
  }
}

// ---------- BN3 + channel-attention MLP gate: reads A, writes D ----------
__global__ __launch_bounds__(256) void k_chatt(const float* __restrict__ A, float* __restrict__ D,
                        const float* __restrict__ sc, const float* __restrict__ sh,
                        const float* __restrict__ w1, const float* __restrict__ b1,
                        const float* __restrict__ w2, const float* __restrict__ b2) {
  int b = blockIdx.x, t = threadIdx.x;
  __shared__ float xin[CC][HW];
  const float* Ab = A + (size_t)b*CC*HW;
  for (int c = 0; c < CC; ++c)
    if (t < HW) xin[c][t] = Ab[c*HW + t]*sc[c] + sh[c];
  __syncthreads();
  if (t < HW) {
    float h[32];
    for (int jg = 0; jg < 2; ++jg) {
      float acc[16];
      #pragma unroll
      for (int j = 0; j < 16; ++j) acc[j] = 0.f;
      for (int ci0 = 0; ci0 < CC; ci0 += 8) {
        float xv[8];
        #pragma unroll
        for (int k = 0; k < 8; ++k) xv[k] = xin[ci0+k][t];
        #pragma unroll
        for (int j = 0; j < 16; ++j) {
          const float* wr = w1 + (size_t)(jg*16 + j)*CC + ci0;
          #pragma unroll
          for (int k = 0; k < 8; ++k) acc[j] += wr[k]*xv[k];
        }
      }
      #pragma unroll
      for (int j = 0; j < 16; ++j) h[jg*16 + j] = fmaxf(acc[j] + b1[jg*16 + j], 0.f);
    }
    float* Db = D + (size_t)b*CC*HW;
    for (int co = 0; co < CC; ++co) {
      const float* wr = w2 + (size_t)co*32;
      float acc = b2[co];
      #pragma unroll
      for (int j = 0; j < 32; ++j) acc += wr[j]*h[j];
      float g = 1.f/(1.f + expf(-acc));
      Db[co*HW + t] = xin[co][t]*g;
    }
  }
}

// ---------- 7x7 conv: 128 -> 32, pad 3, + bias. One block per image, 512 thr ----------
__global__ __launch_bounds__(512) void k_conv7a(const float* __restrict__ D, const float* __restrict__ W,
                         const float* __restrict__ bias, float* __restrict__ S) {
  int b = blockIdx.x, t = threadIdx.x;
  int co = t >> 4, y = t & 15;            // 32 co x 16 rows (row 15 idle)
  __shared__ __align__(16) float xp[64][21][24];   // fully zero-padded, 129 KB
  float acc[15];
  #pragma unroll
  for (int i = 0; i < 15; ++i) acc[i] = 0.f;
  for (int cig = 0; cig < 2; ++cig) {
    float* xf = &xp[0][0][0];
    for (int i = t; i < 64*21*24; i += 512) xf[i] = 0.f;
    __syncthreads();
    const float* Db = D + ((size_t)b*CC + cig*64)*HW;
    for (int i = t; i < 64*HW; i += 512) {
      int ci = i / HW, p = i - ci*HW;
      int py = p / 15, px = p - py*15;
      xp[ci][py+3][px+3] = Db[i];
    }
    __syncthreads();
    if (y < 15) {
      for (int ci = 0; ci < 64; ++ci) {
        const float* wb = W + ((size_t)co*CC + cig*64 + ci)*49;
        #pragma unroll
        for (int ky = 0; ky < 7; ++ky) {
          float wr[7];
          #pragma unroll
          for (int kx = 0; kx < 7; ++kx) wr[kx] = wb[ky*7 + kx];
          const float4* row4 = (const float4*)&xp[ci][y+ky][0];
          float xr[24];
          #pragma unroll
          for (int q = 0; q < 6; ++q) { float4 v = row4[q]; xr[4*q]=v.x; xr[4*q+1]=v.y; xr[4*q+2]=v.z; xr[4*q+3]=v.w; }
          #pragma unroll
          for (int kx = 0; kx < 7; ++kx)
            #pragma unroll
            for (int x = 0; x < 15; ++x) acc[x] += wr[kx]*xr[x+kx];
        }
      }
    }
    __syncthreads();
  }
  if (y < 15) {
    float bv = bias[co];
    #pragma unroll
    for (int x = 0; x < 15; ++x) S[((size_t)b*32 + co)*HW + y*15 + x] = acc[x] + bv;
  }
}

// ---------- 7x7 conv: 32 -> 128, pad 3, input gets BN+relu at staging. 2 blocks/image ----------
__global__ __launch_bounds__(512) void k_conv7b(const float* __restrict__ S,
                         const float* __restrict__ sc, const float* __restrict__ sh,
                         const float* __restrict__ W, const float* __restrict__ bias,
                         float* __restrict__ O) {
  int b = blockIdx.x >> 1, half = blockIdx.x & 1;
  int t = threadIdx.x;
  int co = (t >> 3) + half*64, yg = t & 7;   // 64 co x 8 row-groups; rows {yg, yg+8}
  __shared__ __align__(16) float sp[32][21][24];   // 63 KB
  float acc[2][15];
  #pragma unroll
  for (int r = 0; r < 2; ++r)
    #pragma unroll
    for (int i = 0; i < 15; ++i) acc[r][i] = 0.f;
  float* sf = &sp[0][0][0];
  for (int i = t; i < 32*21*24; i += 512) sf[i] = 0.f;
  __syncthreads();
  const float* Sb = S + (size_t)b*32*HW;
  for (int i = t; i < 32*HW; i += 512) {
    int ci = i / HW, p = i - ci*HW;
    int py = p / 15, px = p - py*15;
    sp[ci][py+3][px+3] = fmaxf(Sb[i]*sc[ci] + sh[ci], 0.f);
  }
  __syncthreads();
  for (int ci = 0; ci < 32; ++ci) {
    const float* wb = W + ((size_t)co*32 + ci)*49;
    #pragma unroll
    for (int ky = 0; ky < 7; ++ky) {
      float wr[7];
      #pragma unroll
      for (int kx = 0; kx < 7; ++kx) wr[kx] = wb[ky*7 + kx];
      #pragma unroll
      for (int r = 0; r < 2; ++r) {
        int y = yg + r*8;
        if (y < 15) {
          const float4* row4 = (const float4*)&sp[ci][y+ky][0];
          float xr[24];
          #pragma unroll
          for (int q = 0; q < 6; ++q) { float4 v = row4[q]; xr[4*q]=v.x; xr[4*q+1]=v.y; xr[4*q+2]=v.z; xr[4*q+3]=v.w; }
          #pragma unroll
          for (int kx = 0; kx < 7; ++kx)
            #pragma unroll
            for (int x = 0; x < 15; ++x) acc[r][x] += wr[kx]*xr[x+kx];
        }
      }
    }
  }
  float bv = bias[co];
  #pragma unroll
  for (int r = 0; r < 2; ++r) {
    int y = yg + r*8;
    if (y < 15)
      #pragma unroll
      for (int x = 0; x < 15; ++x) O[((size_t)b*CC + co)*HW + y*15 + x] = acc[r][x] + bv;
  }
}

// ---------- final: D *= sigmoid(bn5(A)) ----------
__global__ __launch_bounds__(256) void k_final(float* __restrict__ D, const float* __restrict__ A,
                        const float* __restrict__ sc, const float* __restrict__ sh) {
  size_t i = (size_t)blockIdx.x*256 + threadIdx.x;
  int c = (int)((i / HW) % CC);
  float s = A[i]*sc[c] + sh[c];
  D[i] *= 1.f/(1.f + expf(-s));
}

extern "C" void kernel_launch(void* const* d_in, const int* in_sizes, int n_in,
                              void* d_out, int out_size, void* d_ws, size_t ws_size,
                              hipStream_t stream) {
  (void)in_sizes; (void)n_in; (void)out_size; (void)ws_size;
  const float* x1    = (const float*)d_in[0];
  const float* x2    = (const float*)d_in[1];
  const float* lam   = (const float*)d_in[2];
  const float* bn1_g = (const float*)d_in[3];
  const float* bn1_b = (const float*)d_in[4];
  const float* pW1   = (const float*)d_in[5];
  const float* dW1   = (const float*)d_in[6];
  const float* db1   = (const float*)d_in[7];
  const float* bn2_g = (const float*)d_in[8];
  const float* bn2_b = (const float*)d_in[9];
  const float* pW2   = (const float*)d_in[10];
  const float* dW2   = (const float*)d_in[11];
  const float* db2   = (const float*)d_in[12];
  const float* qkvW  = (const float*)d_in[13];
  const float* bn3_g = (const float*)d_in[14];
  const float* bn3_b = (const float*)d_in[15];
  const float* ca_w1 = (const float*)d_in[16];
  const float* ca_b1 = (const float*)d_in[17];
  const float* ca_w2 = (const float*)d_in[18];
  const float* ca_b2 = (const float*)d_in[19];
  const float* sa_w1 = (const float*)d_in[20];
  const float* sa_b1 = (const float*)d_in[21];
  const float* sbn1_g= (const float*)d_in[22];
  const float* sbn1_b= (const float*)d_in[23];
  const float* sa_w2 = (const float*)d_in[24];
  const float* sa_b2 = (const float*)d_in[25];
  const float* sbn2_g= (const float*)d_in[26];
  const float* sbn2_b= (const float*)d_in[27];

  float* D = (float*)d_out;
  float* A = (float*)d_ws;                         // (512,128,225) f32
  float* S = A + (size_t)BB*CC*HW;                 // (512,32,225)  f32
  float* st = S + (size_t)BB*32*HW;                // stats scratch
  float *sc1 = st,     *sh1 = st+128, *sc2 = st+256, *sh2 = st+384,
        *sc3 = st+512, *sh3 = st+640, *sc4 = st+768, *sh4 = st+800,
        *sc5 = st+832, *sh5 = st+960;

  k_attn1 <<<BB, 256, 0, stream>>>(x1, x2, lam, A);
  k_bnstats<<<CC, 256, 0, stream>>>(A, CC, bn1_g, bn1_b, sc1, sh1);
  k_pw<1> <<<BB, 256, 0, stream>>>(A, pW1, sc1, sh1, dW1, db1);
  k_bnstats<<<CC, 256, 0, stream>>>(A, CC, bn2_g, bn2_b, sc2, sh2);
  k_pw<2> <<<BB, 256, 0, stream>>>(A, pW2, sc2, sh2, nullptr, nullptr);
  k_dw3   <<<BB, 256, 0, stream>>>(A, dW2, db2);
  k_attn2 <<<BB, 256, 0, stream>>>(A, qkvW);
  k_bnstats<<<CC, 256, 0, stream>>>(A, CC, bn3_g, bn3_b, sc3, sh3);
  k_chatt <<<BB, 256, 0, stream>>>(A, D, sc3, sh3, ca_w1, ca_b1, ca_w2, ca_b2);
  k_conv7a<<<BB, 512, 0, stream>>>(D, sa_w1, sa_b1, S);
  k_bnstats<<<32, 256, 0, stream>>>(S, 32, sbn1_g, sbn1_b, sc4, sh4);
  k_conv7b<<<BB*2, 512, 0, stream>>>(S, sc4, sh4, sa_w2, sa_b2, A);
  k_bnstats<<<CC, 256, 0, stream>>>(A, CC, sbn2_g, sbn2_b, sc5, sh5);
  k_final <<<(BB*CC*HW)/256, 256, 0, stream>>>(D, A, sc5, sh5);
}

// Round 2
// 2059.762 us; speedup vs baseline: 2.7634x; 2.7634x over previous
//
#include <hip/hip_runtime.h>
#include <hip/hip_bf16.h>
#include <cmath>

#define BB 512
#define CC 128
#define HW 225

typedef __attribute__((ext_vector_type(8))) short short8;
typedef __attribute__((ext_vector_type(4))) float f32x4;

// ---------- block reduction helpers (blockDim == 256) ----------
__device__ __forceinline__ float block_reduce_max(float v, float* red, int t) {
  red[t] = v; __syncthreads();
  for (int st = 128; st > 0; st >>= 1) { if (t < st) red[t] = fmaxf(red[t], red[t+st]); __syncthreads(); }
  float r = red[0]; __syncthreads();
  return r;
}
__device__ __forceinline__ float block_reduce_sum(float v, float* red, int t) {
  red[t] = v; __syncthreads();
  for (int st = 128; st > 0; st >>= 1) { if (t < st) red[t] += red[t+st]; __syncthreads(); }
  float r = red[0]; __syncthreads();
  return r;
}

// ---------- BN stats stage 1: grid (C, 16), 32 images per block ----------
__global__ __launch_bounds__(256) void k_bnstats2(const float* __restrict__ x, int C,
                           float* __restrict__ part) {
  int c = blockIdx.x, chunk = blockIdx.y, t = threadIdx.x;
  float s = 0.f, q = 0.f;
  for (int b = chunk*32; b < chunk*32 + 32; ++b) {
    const float* row = x + ((size_t)b*C + c)*HW;
    if (t < HW) { float v = row[t]; s += v; q += v*v; }
  }
  __shared__ float rs[256], rq[256];
  rs[t] = s; rq[t] = q; __syncthreads();
  for (int st = 128; st > 0; st >>= 1) { if (t < st) { rs[t]+=rs[t+st]; rq[t]+=rq[t+st]; } __syncthreads(); }
  if (t == 0) { part[(c*16 + chunk)*2] = rs[0]; part[(c*16 + chunk)*2 + 1] = rq[0]; }
}

// ---------- BN stats stage 2: one block, C threads ----------
__global__ void k_bnfin(const float* __restrict__ part, int C,
                        const float* __restrict__ g, const float* __restrict__ bt,
                        float* __restrict__ scale, float* __restrict__ shift) {
  int c = threadIdx.x;
  if (c >= C) return;
  float s = 0.f, q = 0.f;
  for (int k = 0; k < 16; ++k) { s += part[(c*16+k)*2]; q += part[(c*16+k)*2+1]; }
  const float N = (float)BB*HW;
  float mean = s/N, var = q/N - mean*mean;
  float sc = g[c]*rsqrtf(var + 1e-5f);
  scale[c] = sc; shift[c] = bt[c] - mean*sc;
}

// ---------- attention 1 (concat + center-similarity attention), writes A ----------
__global__ __launch_bounds__(256) void k_attn1(const float* __restrict__ x1, const float* __restrict__ x2,
                        const float* __restrict__ lam, float* __restrict__ A) {
  int b = blockIdx.x, t = threadIdx.x;
  __shared__ float cent[CC];
  __shared__ float red[256];
  const float* xb1 = x1 + (size_t)b*64*HW;
  const float* xb2 = x2 + (size_t)b*64*HW;
  if (t < CC) cent[t] = (t < 64) ? xb1[t*HW + 112] : xb2[(t-64)*HW + 112];
  __syncthreads();
  float e2 = 0.f, dot = 0.f, qn2 = 0.f, cn2 = 0.f;
  if (t < HW) {
    for (int c = 0; c < CC; ++c) {
      float xv = (c < 64) ? xb1[c*HW + t] : xb2[(c-64)*HW + t];
      float ce = cent[c];
      float d = xv - ce;
      e2 += d*d; dot += xv*ce; qn2 += xv*xv; cn2 += ce*ce;
    }
  }
  float sim_e = 0.f, sim_c = 0.f;
  if (t < HW) {
    sim_e = 1.f/(1.f + sqrtf(e2));
    float qn = sqrtf(qn2), cn = sqrtf(cn2);
    sim_c = dot / (fmaxf(cn, 1e-8f) * fmaxf(qn, 1e-8f));
  }
  float m1 = block_reduce_max((t<HW)? sim_e : -1e30f, red, t);
  float e1v = (t<HW)? expf(sim_e - m1) : 0.f;
  float s1 = block_reduce_sum(e1v, red, t);
  float m2 = block_reduce_max((t<HW)? sim_c : -1e30f, red, t);
  float e2v = (t<HW)? expf(sim_c - m2) : 0.f;
  float s2 = block_reduce_sum(e2v, red, t);
  float lmd = 1.f/(1.f + expf(-lam[0]));
  float am = 1.f + lmd*e1v/s1 + (1.f - lmd)*e2v/s2;
  if (t < HW) {
    float* Ab = A + (size_t)b*CC*HW;
    for (int c = 0; c < CC; ++c) {
      float xv = (c < 64) ? xb1[c*HW + t] : xb2[(c-64)*HW + t];
      Ab[c*HW + t] = xv*am;
    }
  }
}

// ---------- fused BN + 1x1 conv (+ optional dw1x1+bias+relu), in-place on A ----------
template<int MODE>
__global__ __launch_bounds__(256) void k_pw(float* __restrict__ A, const float* __restrict__ W,
                     const float* __restrict__ scale, const float* __restrict__ shift,
                     const float* __restrict__ dw, const float* __restrict__ db) {
  int b = blockIdx.x, t = threadIdx.x;
  __shared__ float xin[CC][HW];
  float* Ab = A + (size_t)b*CC*HW;
  for (int c = 0; c < CC; ++c)
    if (t < HW) xin[c][t] = Ab[c*HW + t]*scale[c] + shift[c];
  __syncthreads();
  if (t < HW) {
    for (int cog = 0; cog < CC/16; ++cog) {
      float acc[16];
      #pragma unroll
      for (int j = 0; j < 16; ++j) acc[j] = 0.f;
      for (int ci0 = 0; ci0 < CC; ci0 += 8) {
        float xv[8];
        #pragma unroll
        for (int k = 0; k < 8; ++k) xv[k] = xin[ci0+k][t];
        #pragma unroll
        for (int j = 0; j < 16; ++j) {
          const float* wr = W + (size_t)(cog*16 + j)*CC + ci0;
          #pragma unroll
          for (int k = 0; k < 8; ++k) acc[j] += wr[k]*xv[k];
        }
      }
      #pragma unroll
      for (int j = 0; j < 16; ++j) {
        int co = cog*16 + j;
        float y = acc[j];
        y = (y >= 0.f) ? y : 0.01f*y;
        if (MODE == 1) { y = y*dw[co] + db[co]; y = fmaxf(y, 0.f); }
        Ab[co*HW + t] = y;
      }
    }
  }
}

// ---------- depthwise 3x3 pad1 + bias + relu, in-place ----------
__global__ __launch_bounds__(256) void k_dw3(float* __restrict__ A, const float* __restrict__ w,
                      const float* __restrict__ db) {
  int b = blockIdx.x, t = threadIdx.x;
  __shared__ float xin[CC][HW];
  float* Ab = A + (size_t)b*CC*HW;
  for (int c = 0; c < CC; ++c)
    if (t < HW) xin[c][t] = Ab[c*HW + t];
  __syncthreads();
  if (t < HW) {
    int y = t/15, x = t - y*15;
    for (int c = 0; c < CC; ++c) {
      float acc = db[c];
      #pragma unroll
      for (int ky = 0; ky < 3; ++ky) {
        int iy = y + ky - 1;
        if (iy < 0 || iy >= 15) continue;
        #pragma unroll
        for (int kx = 0; kx < 3; ++kx) {
          int ix = x + kx - 1;
          if (ix < 0 || ix >= 15) continue;
          acc += w[c*9 + ky*3 + kx]*xin[c][iy*15 + ix];
        }
      }
      Ab[c*HW + t] = fmaxf(acc, 0.f);
    }
  }
}

// ---------- attention 2 (K/V proj + center-distance attention + residual), in-place ----------
__global__ __launch_bounds__(256) void k_attn2(float* __restrict__ A, const float* __restrict__ Wqkv) {
  int b = blockIdx.x, t = threadIdx.x;
  __shared__ float xin[CC][HW];
  __shared__ float cent[CC];
  __shared__ float red[256];
  float* Ab = A + (size_t)b*CC*HW;
  for (int c = 0; c < CC; ++c)
    if (t < HW) xin[c][t] = Ab[c*HW + t];
  __syncthreads();
  if (t < CC) {
    const float* wq = Wqkv + (size_t)t*CC;
    float acc = 0.f;
    for (int ci = 0; ci < CC; ++ci) acc += wq[ci]*xin[ci][112];
    cent[t] = acc;
  }
  __syncthreads();
  float e2 = 0.f;
  if (t < HW) {
    const float* Wk = Wqkv + (size_t)CC*CC;
    for (int cog = 0; cog < 8; ++cog) {
      float acc[16];
      #pragma unroll
      for (int j = 0; j < 16; ++j) acc[j] = 0.f;
      for (int ci0 = 0; ci0 < CC; ci0 += 8) {
        float xv[8];
        #pragma unroll
        for (int k = 0; k < 8; ++k) xv[k] = xin[ci0+k][t];
        #pragma unroll
        for (int j = 0; j < 16; ++j) {
          const float* wr = Wk + (size_t)(cog*16 + j)*CC + ci0;
          #pragma unroll
          for (int k = 0; k < 8; ++k) acc[j] += wr[k]*xv[k];
        }
      }
      #pragma unroll
      for (int j = 0; j < 16; ++j) { float d = cent[cog*16 + j] - acc[j]; e2 += d*d; }
    }
  }
  float sim = (t < HW) ? 1.f/(1.f + sqrtf(e2)) : 0.f;
  float m = block_reduce_max((t<HW)? sim : -1e30f, red, t);
  float ev = (t<HW)? expf(sim - m) : 0.f;
  float s = block_reduce_sum(ev, red, t);
  float att = ev/s;
  if (t < HW) {
    const float* Wv = Wqkv + (size_t)2*CC*CC;
    for (int cog = 0; cog < 8; ++cog) {
      float acc[16];
      #pragma unroll
      for (int j = 0; j < 16; ++j) acc[j] = 0.f;
      for (int ci0 = 0; ci0 < CC; ci0 += 8) {
        float xv[8];
        #pragma unroll
        for (int k = 0; k < 8; ++k) xv[k] = xin[ci0+k][t];
        #pragma unroll
        for (int j = 0; j < 16; ++j) {
          const float* wr = Wv + (size_t)(cog*16 + j)*CC + ci0;
          #pragma unroll
          for (int k = 0; k < 8; ++k) acc[j] += wr[k]*xv[k];
        }
      }
      #pragma unroll
      for (int j = 0; j < 16; ++j) {
        int co = cog*16 + j;
        Ab[co*HW + t] = att*acc[j] + xin[co][t];
      }
    }
  }
}

// ---------- BN3 + channel-attention MLP gate: reads A, writes D ----------
__global__ __launch_bounds__(256) void k_chatt(const float* __restrict__ A, float* __restrict__ D,
                        const float* __restrict__ sc, const float* __restrict__ sh,
                        const float* __restrict__ w1, const float* __restrict__ b1,
                        const float* __restrict__ w2, const float* __restrict__ b2) {
  int b = blockIdx.x, t = threadIdx.x;
  __shared__ float xin[CC][HW];
  const float* Ab = A + (size_t)b*CC*HW;
  for (int c = 0; c < CC; ++c)
    if (t < HW) xin[c][t] = Ab[c*HW + t]*sc[c] + sh[c];
  __syncthreads();
  if (t < HW) {
    float h[32];
    for (int jg = 0; jg < 2; ++jg) {
      float acc[16];
      #pragma unroll
      for (int j = 0; j < 16; ++j) acc[j] = 0.f;
      for (int ci0 = 0; ci0 < CC; ci0 += 8) {
        float xv[8];
        #pragma unroll
        for (int k = 0; k < 8; ++k) xv[k] = xin[ci0+k][t];
        #pragma unroll
        for (int j = 0; j < 16; ++j) {
          const float* wr = w1 + (size_t)(jg*16 + j)*CC + ci0;
          #pragma unroll
          for (int k = 0; k < 8; ++k) acc[j] += wr[k]*xv[k];
        }
      }
      #pragma unroll
      for (int j = 0; j < 16; ++j) h[jg*16 + j] = fmaxf(acc[j] + b1[jg*16 + j], 0.f);
    }
    float* Db = D + (size_t)b*CC*HW;
    for (int co = 0; co < CC; ++co) {
      const float* wr = w2 + (size_t)co*32;
      float acc = b2[co];
      #pragma unroll
      for (int j = 0; j < 32; ++j) acc += wr[j]*h[j];
      float g = 1.f/(1.f + expf(-acc));
      Db[co*HW + t] = xin[co][t]*g;
    }
  }
}

// ---------- weight pre-pack into MFMA fragment order (bf16) ----------
// Wa layout: [s(49)][cs(4)][ct(2)][lane(64)][j(8)] ; co=ct*16+(l&15), ci=cs*32+(l>>4)*8+j
__global__ void k_prep_wa(const float* __restrict__ w, unsigned short* __restrict__ Wa) {
  int id = blockIdx.x*256 + threadIdx.x;
  if (id >= 49*4*2*64*8) return;
  int j = id & 7, l = (id >> 3) & 63, ct = (id >> 9) & 1, cs = (id >> 10) & 3, s = id >> 12;
  int co = ct*16 + (l & 15);
  int ci = cs*32 + ((l >> 4) << 3) + j;
  __hip_bfloat16 h = __float2bfloat16(w[(co*128 + ci)*49 + s]);
  Wa[id] = *(unsigned short*)&h;
}
// Wb layout: [s(49)][ct(8)][lane(64)][j(8)] ; co=ct*16+(l&15), ci=(l>>4)*8+j
__global__ void k_prep_wb(const float* __restrict__ w, unsigned short* __restrict__ Wb) {
  int id = blockIdx.x*256 + threadIdx.x;
  if (id >= 49*8*64*8) return;
  int j = id & 7, l = (id >> 3) & 63, ct = (id >> 9) & 7, s = id >> 12;
  int co = ct*16 + (l & 15);
  int ci = ((l >> 4) << 3) + j;
  __hip_bfloat16 h = __float2bfloat16(w[(co*32 + ci)*49 + s]);
  Wb[id] = *(unsigned short*)&h;
}

// ---------- 7x7 conv 128->32 as 49 shifted 1x1 GEMMs, MFMA bf16. One block/image ----------
#define CIP_A 136   // padded ci stride (ushorts): 272 B, 16B-aligned
__global__ __launch_bounds__(512) void k_conv7a_mfma(const float* __restrict__ D,
        const unsigned short* __restrict__ Wa, float* __restrict__ S) {
  int b = blockIdx.x, t = threadIdx.x;
  __shared__ __align__(16) unsigned short xb[21*22*CIP_A];   // 125,664 B
  unsigned int* xw = (unsigned int*)xb;
  for (int i = t; i < 21*22*CIP_A/2; i += 512) xw[i] = 0u;
  __syncthreads();
  const float* Db = D + (size_t)b*CC*HW;
  for (int i = t; i < CC*HW; i += 512) {
    int ci = i / HW, p = i - ci*HW;
    int y = p/15, x = p - y*15;
    __hip_bfloat16 h = __float2bfloat16(Db[i]);
    xb[((y+3)*22 + (x+3))*CIP_A + ci] = *(unsigned short*)&h;
  }
  __syncthreads();
  int w = t >> 6, l = t & 63;
  int g = l >> 4, x = l & 15;
  int nt0 = w, nt1 = w + 8;               // output rows; nt1 valid if < 15
  f32x4 acc[2][2] = {};
  const short8* wp = (const short8*)Wa;
  for (int s = 0; s < 49; ++s) {
    int dy = s / 7, dx = s % 7;
    for (int cs = 0; cs < 4; ++cs) {
      short8 a0 = wp[((s*4 + cs)*2 + 0)*64 + l];
      short8 a1 = wp[((s*4 + cs)*2 + 1)*64 + l];
      short8 b0 = *(const short8*)&xb[((nt0+dy)*22 + (x+dx))*CIP_A + cs*32 + g*8];
      acc[0][0] = __builtin_amdgcn_mfma_f32_16x16x32_bf16(a0, b0, acc[0][0], 0, 0, 0);
      acc[1][0] = __builtin_amdgcn_mfma_f32_16x16x32_bf16(a1, b0, acc[1][0], 0, 0, 0);
      if (nt1 < 15) {
        short8 b1 = *(const short8*)&xb[((nt1+dy)*22 + (x+dx))*CIP_A + cs*32 + g*8];
        acc[0][1] = __builtin_amdgcn_mfma_f32_16x16x32_bf16(a0, b1, acc[0][1], 0, 0, 0);
        acc[1][1] = __builtin_amdgcn_mfma_f32_16x16x32_bf16(a1, b1, acc[1][1], 0, 0, 0);
      }
    }
  }
  // D-frag: col(x)=l&15, row(m)=(l>>4)*4+r.  (sa_b1 dropped: absorbed by following BN)
  if (x < 15) {
    for (int ct = 0; ct < 2; ++ct)
      for (int ni = 0; ni < 2; ++ni) {
        int nt = ni ? nt1 : nt0;
        if (nt >= 15) continue;
        float* out = S + ((size_t)b*32 + ct*16 + g*4)*HW + nt*15 + x;
        #pragma unroll
        for (int r = 0; r < 4; ++r) out[r*HW] = acc[ct][ni][r];
      }
  }
}

// ---------- 7x7 conv 32->128, input gets BN+relu at staging. One block/image ----------
#define CIP_B 40    // padded ci stride (ushorts): 80 B, 16B-aligned
__global__ __launch_bounds__(512) void k_conv7b_mfma(const float* __restrict__ S,
        const float* __restrict__ sc, const float* __restrict__ sh,
        const unsigned short* __restrict__ Wb, float* __restrict__ O) {
  int b = blockIdx.x, t = threadIdx.x;
  __shared__ __align__(16) unsigned short xb[21*22*CIP_B];   // 36,960 B
  unsigned int* xw = (unsigned int*)xb;
  for (int i = t; i < 21*22*CIP_B/2; i += 512) xw[i] = 0u;
  __syncthreads();
  const float* Sb = S + (size_t)b*32*HW;
  for (int i = t; i < 32*HW; i += 512) {
    int ci = i / HW, p = i - ci*HW;
    int y = p/15, xx = p - y*15;
    float v = fmaxf(Sb[i]*sc[ci] + sh[ci], 0.f);
    __hip_bfloat16 h = __float2bfloat16(v);
    xb[((y+3)*22 + (xx+3))*CIP_B + ci] = *(unsigned short*)&h;
  }
  __syncthreads();
  int w = t >> 6, l = t & 63;
  int g = l >> 4, x = l & 15;
  int nt0 = w, nt1 = w + 8;
  f32x4 acc[8][2] = {};
  const short8* wp = (const short8*)Wb;
  for (int s = 0; s < 49; ++s) {
    int dy = s / 7, dx = s % 7;
    short8 b0 = *(const short8*)&xb[((nt0+dy)*22 + (x+dx))*CIP_B + g*8];
    short8 b1 = b0;
    if (nt1 < 15) b1 = *(const short8*)&xb[((nt1+dy)*22 + (x+dx))*CIP_B + g*8];
    #pragma unroll
    for (int ct = 0; ct < 8; ++ct) {
      short8 a = wp[(s*8 + ct)*64 + l];
      acc[ct][0] = __builtin_amdgcn_mfma_f32_16x16x32_bf16(a, b0, acc[ct][0], 0, 0, 0);
      if (nt1 < 15) acc[ct][1] = __builtin_amdgcn_mfma_f32_16x16x32_bf16(a, b1, acc[ct][1], 0, 0, 0);
    }
  }
  if (x < 15) {
    for (int ct = 0; ct < 8; ++ct)
      for (int ni = 0; ni < 2; ++ni) {
        int nt = ni ? nt1 : nt0;
        if (nt >= 15) continue;
        float* out = O + ((size_t)b*CC + ct*16 + g*4)*HW + nt*15 + x;
        #pragma unroll
        for (int r = 0; r < 4; ++r) out[r*HW] = acc[ct][ni][r];
      }
  }
}

// ---------- final: D *= sigmoid(bn5(A)) ----------
__global__ __launch_bounds__(256) void k_final(float* __restrict__ D, const float* __restrict__ A,
                        const float* __restrict__ sc, const float* __restrict__ sh) {
  size_t i = (size_t)blockIdx.x*256 + threadIdx.x;
  int c = (int)((i / HW) % CC);
  float s = A[i]*sc[c] + sh[c];
  D[i] *= 1.f/(1.f + expf(-s));
}

extern "C" void kernel_launch(void* const* d_in, const int* in_sizes, int n_in,
                              void* d_out, int out_size, void* d_ws, size_t ws_size,
                              hipStream_t stream) {
  (void)in_sizes; (void)n_in; (void)out_size; (void)ws_size;
  const float* x1    = (const float*)d_in[0];
  const float* x2    = (const float*)d_in[1];
  const float* lam   = (const float*)d_in[2];
  const float* bn1_g = (const float*)d_in[3];
  const float* bn1_b = (const float*)d_in[4];
  const float* pW1   = (const float*)d_in[5];
  const float* dW1   = (const float*)d_in[6];
  const float* db1   = (const float*)d_in[7];
  const float* bn2_g = (const float*)d_in[8];
  const float* bn2_b = (const float*)d_in[9];
  const float* pW2   = (const float*)d_in[10];
  const float* dW2   = (const float*)d_in[11];
  const float* db2   = (const float*)d_in[12];
  const float* qkvW  = (const float*)d_in[13];
  const float* bn3_g = (const float*)d_in[14];
  const float* bn3_b = (const float*)d_in[15];
  const float* ca_w1 = (const float*)d_in[16];
  const float* ca_b1 = (const float*)d_in[17];
  const float* ca_w2 = (const float*)d_in[18];
  const float* ca_b2 = (const float*)d_in[19];
  const float* sa_w1 = (const float*)d_in[20];
  const float* sbn1_g= (const float*)d_in[22];
  const float* sbn1_b= (const float*)d_in[23];
  const float* sa_w2 = (const float*)d_in[24];
  const float* sbn2_g= (const float*)d_in[26];
  const float* sbn2_b= (const float*)d_in[27];

  float* D = (float*)d_out;
  float* A = (float*)d_ws;                          // (512,128,225) f32
  float* S = A + (size_t)BB*CC*HW;                  // (512,32,225)  f32
  float* part = S + (size_t)BB*32*HW;               // 4096 f32 partials (reused)
  float* st = part + 4096;
  float *sc1 = st,      *sh1 = st+128,  *sc2 = st+256, *sh2 = st+384,
        *sc3 = st+512,  *sh3 = st+640,  *sc4 = st+768, *sh4 = st+800,
        *sc5 = st+832,  *sh5 = st+960;
  unsigned short* Wa = (unsigned short*)(st + 1280);   // 49*4096 bf16
  unsigned short* Wb = Wa + 49*4096;                   // 49*4096 bf16

  k_prep_wa<<<784, 256, 0, stream>>>(sa_w1, Wa);
  k_prep_wb<<<784, 256, 0, stream>>>(sa_w2, Wb);

  k_attn1 <<<BB, 256, 0, stream>>>(x1, x2, lam, A);
  k_bnstats2<<<dim3(CC,16), 256, 0, stream>>>(A, CC, part);
  k_bnfin <<<1, CC, 0, stream>>>(part, CC, bn1_g, bn1_b, sc1, sh1);
  k_pw<1> <<<BB, 256, 0, stream>>>(A, pW1, sc1, sh1, dW1, db1);
  k_bnstats2<<<dim3(CC,16), 256, 0, stream>>>(A, CC, part);
  k_bnfin <<<1, CC, 0, stream>>>(part, CC, bn2_g, bn2_b, sc2, sh2);
  k_pw<2> <<<BB, 256, 0, stream>>>(A, pW2, sc2, sh2, nullptr, nullptr);
  k_dw3   <<<BB, 256, 0, stream>>>(A, dW2, db2);
  k_attn2 <<<BB, 256, 0, stream>>>(A, qkvW);
  k_bnstats2<<<dim3(CC,16), 256, 0, stream>>>(A, CC, part);
  k_bnfin <<<1, CC, 0, stream>>>(part, CC, bn3_g, bn3_b, sc3, sh3);
  k_chatt <<<BB, 256, 0, stream>>>(A, D, sc3, sh3, ca_w1, ca_b1, ca_w2, ca_b2);
  k_conv7a_mfma<<<BB, 512, 0, stream>>>(D, Wa, S);
  k_bnstats2<<<dim3(32,16), 256, 0, stream>>>(S, 32, part);
  k_bnfin <<<1, 32, 0, stream>>>(part, 32, sbn1_g, sbn1_b, sc4, sh4);
  k_conv7b_mfma<<<BB, 512, 0, stream>>>(S, sc4, sh4, Wb, A);
  k_bnstats2<<<dim3(CC,16), 256, 0, stream>>>(A, CC, part);
  k_bnfin <<<1, CC, 0, stream>>>(part, CC, sbn2_g, sbn2_b, sc5, sh5);
  k_final <<<(BB*CC*HW)/256, 256, 0, stream>>>(D, A, sc5, sh5);
}

// Round 3
// 674.125 us; speedup vs baseline: 8.4434x; 3.0555x over previous
//
#include <hip/hip_runtime.h>
#include <hip/hip_bf16.h>
#include <cmath>

#define BB 512
#define CC 128
#define HW 225
#define CIP 136     // ushort stride for 128-ci LDS rows (272 B, 16B-aligned)
#define CIPH 40     // ushort stride for 32-ch hidden rows

typedef __attribute__((ext_vector_type(8))) short short8;
typedef __attribute__((ext_vector_type(4))) float f32x4;

__device__ __forceinline__ unsigned short f2bf(float v) {
  __hip_bfloat16 h = __float2bfloat16(v);
  return *(unsigned short*)&h;
}
__device__ __forceinline__ float bf2f(unsigned short u) {
  __hip_bfloat16 h = *(__hip_bfloat16*)&u;
  return __bfloat162float(h);
}

// ---------- block reduction helpers (blockDim == 256) ----------
__device__ __forceinline__ float block_reduce_max(float v, float* red, int t) {
  red[t] = v; __syncthreads();
  for (int st = 128; st > 0; st >>= 1) { if (t < st) red[t] = fmaxf(red[t], red[t+st]); __syncthreads(); }
  float r = red[0]; __syncthreads();
  return r;
}
__device__ __forceinline__ float block_reduce_sum(float v, float* red, int t) {
  red[t] = v; __syncthreads();
  for (int st = 128; st > 0; st >>= 1) { if (t < st) red[t] += red[t+st]; __syncthreads(); }
  float r = red[0]; __syncthreads();
  return r;
}

// ---------- BN stats: stage 1 (C,16 chunks), stage 2 finalize ----------
__global__ __launch_bounds__(256) void k_bnstats2(const float* __restrict__ x, int C,
                           float* __restrict__ part) {
  int c = blockIdx.x, chunk = blockIdx.y, t = threadIdx.x;
  float s = 0.f, q = 0.f;
  for (int b = chunk*32; b < chunk*32 + 32; ++b) {
    const float* row = x + ((size_t)b*C + c)*HW;
    if (t < HW) { float v = row[t]; s += v; q += v*v; }
  }
  __shared__ float rs[256], rq[256];
  rs[t] = s; rq[t] = q; __syncthreads();
  for (int st = 128; st > 0; st >>= 1) { if (t < st) { rs[t]+=rs[t+st]; rq[t]+=rq[t+st]; } __syncthreads(); }
  if (t == 0) { part[(c*16 + chunk)*2] = rs[0]; part[(c*16 + chunk)*2 + 1] = rq[0]; }
}
__global__ void k_bnfin(const float* __restrict__ part, int C,
                        const float* __restrict__ g, const float* __restrict__ bt,
                        float* __restrict__ scale, float* __restrict__ shift) {
  int c = threadIdx.x;
  if (c >= C) return;
  float s = 0.f, q = 0.f;
  for (int k = 0; k < 16; ++k) { s += part[(c*16+k)*2]; q += part[(c*16+k)*2+1]; }
  const float N = (float)BB*HW;
  float mean = s/N, var = q/N - mean*mean;
  float sc = g[c]*rsqrtf(var + 1e-5f);
  scale[c] = sc; shift[c] = bt[c] - mean*sc;
}

// ---------- attention 1 ----------
__global__ __launch_bounds__(256) void k_attn1(const float* __restrict__ x1, const float* __restrict__ x2,
                        const float* __restrict__ lam, float* __restrict__ A) {
  int b = blockIdx.x, t = threadIdx.x;
  __shared__ float cent[CC];
  __shared__ float red[256];
  const float* xb1 = x1 + (size_t)b*64*HW;
  const float* xb2 = x2 + (size_t)b*64*HW;
  if (t < CC) cent[t] = (t < 64) ? xb1[t*HW + 112] : xb2[(t-64)*HW + 112];
  __syncthreads();
  float e2 = 0.f, dot = 0.f, qn2 = 0.f, cn2 = 0.f;
  if (t < HW) {
    for (int c = 0; c < CC; ++c) {
      float xv = (c < 64) ? xb1[c*HW + t] : xb2[(c-64)*HW + t];
      float ce = cent[c];
      float d = xv - ce;
      e2 += d*d; dot += xv*ce; qn2 += xv*xv; cn2 += ce*ce;
    }
  }
  float sim_e = 0.f, sim_c = 0.f;
  if (t < HW) {
    sim_e = 1.f/(1.f + sqrtf(e2));
    float qn = sqrtf(qn2), cn = sqrtf(cn2);
    sim_c = dot / (fmaxf(cn, 1e-8f) * fmaxf(qn, 1e-8f));
  }
  float m1 = block_reduce_max((t<HW)? sim_e : -1e30f, red, t);
  float e1v = (t<HW)? expf(sim_e - m1) : 0.f;
  float s1 = block_reduce_sum(e1v, red, t);
  float m2 = block_reduce_max((t<HW)? sim_c : -1e30f, red, t);
  float e2v = (t<HW)? expf(sim_c - m2) : 0.f;
  float s2 = block_reduce_sum(e2v, red, t);
  float lmd = 1.f/(1.f + expf(-lam[0]));
  float am = 1.f + lmd*e1v/s1 + (1.f - lmd)*e2v/s2;
  if (t < HW) {
    float* Ab = A + (size_t)b*CC*HW;
    for (int c = 0; c < CC; ++c) {
      float xv = (c < 64) ? xb1[c*HW + t] : xb2[(c-64)*HW + t];
      Ab[c*HW + t] = xv*am;
    }
  }
}

// ---------- weight pre-pack kernels ----------
// pw weights (128x128) -> hi/lo frags [cs4][ct8][lane64][j8]
__global__ void k_prep_pw(const float* __restrict__ W, unsigned short* __restrict__ Whi,
                          unsigned short* __restrict__ Wlo) {
  int id = blockIdx.x*256 + threadIdx.x;
  if (id >= 16384) return;
  int j = id & 7, l = (id >> 3) & 63, ct = (id >> 9) & 7, cs = id >> 12;
  int co = ct*16 + (l & 15);
  int ci = cs*32 + ((l >> 4) << 3) + j;
  float v = W[co*128 + ci];
  __hip_bfloat16 h = __float2bfloat16(v);
  float hf = __bfloat162float(h);
  __hip_bfloat16 lo = __float2bfloat16(v - hf);
  Whi[id] = *(unsigned short*)&h;
  Wlo[id] = *(unsigned short*)&lo;
}
// K/V weights from qkv_W (rows 128..255 = K, 256..383 = V), single bf16
__global__ void k_prep_kv(const float* __restrict__ Wq, unsigned short* __restrict__ Wk,
                          unsigned short* __restrict__ Wv) {
  int id = blockIdx.x*256 + threadIdx.x;
  if (id >= 16384) return;
  int j = id & 7, l = (id >> 3) & 63, ct = (id >> 9) & 7, cs = id >> 12;
  int co = ct*16 + (l & 15);
  int ci = cs*32 + ((l >> 4) << 3) + j;
  Wk[id] = f2bf(Wq[(size_t)(128 + co)*128 + ci]);
  Wv[id] = f2bf(Wq[(size_t)(256 + co)*128 + ci]);
}
// channel-attention W1 (32x128) -> [cs4][ct2][64][8]
__global__ void k_prep_ca1(const float* __restrict__ w1, unsigned short* __restrict__ Wc1) {
  int id = blockIdx.x*256 + threadIdx.x;
  if (id >= 4096) return;
  int j = id & 7, l = (id >> 3) & 63, ct = (id >> 9) & 1, cs = (id >> 10) & 3;
  int co = ct*16 + (l & 15);
  int ci = cs*32 + ((l >> 4) << 3) + j;
  Wc1[id] = f2bf(w1[co*128 + ci]);
}
// channel-attention W2 (128x32) -> [ct8][64][8]
__global__ void k_prep_ca2(const float* __restrict__ w2, unsigned short* __restrict__ Wc2) {
  int id = blockIdx.x*256 + threadIdx.x;
  if (id >= 4096) return;
  int j = id & 7, l = (id >> 3) & 63, ct = (id >> 9) & 7;
  int co = ct*16 + (l & 15);
  int ci = ((l >> 4) << 3) + j;
  Wc2[id] = f2bf(w2[co*32 + ci]);
}
// conv7 weight packs (from round 2)
__global__ void k_prep_wa(const float* __restrict__ w, unsigned short* __restrict__ Wa) {
  int id = blockIdx.x*256 + threadIdx.x;
  if (id >= 49*4*2*64*8) return;
  int j = id & 7, l = (id >> 3) & 63, ct = (id >> 9) & 1, cs = (id >> 10) & 3, s = id >> 12;
  int co = ct*16 + (l & 15);
  int ci = cs*32 + ((l >> 4) << 3) + j;
  Wa[id] = f2bf(w[(co*128 + ci)*49 + s]);
}
__global__ void k_prep_wb(const float* __restrict__ w, unsigned short* __restrict__ Wb) {
  int id = blockIdx.x*256 + threadIdx.x;
  if (id >= 49*8*64*8) return;
  int j = id & 7, l = (id >> 3) & 63, ct = (id >> 9) & 7, s = id >> 12;
  int co = ct*16 + (l & 15);
  int ci = ((l >> 4) << 3) + j;
  Wb[id] = f2bf(w[(co*32 + ci)*49 + s]);
}

// ---------- fused BN + 1x1 conv via split-bf16 MFMA, in-place on A ----------
// MODE 1: leaky -> *dw + db -> relu      MODE 2: leaky only
template<int MODE>
__global__ __launch_bounds__(512) void k_pw_mfma(float* __restrict__ A,
        const unsigned short* __restrict__ Whi, const unsigned short* __restrict__ Wlo,
        const float* __restrict__ scale, const float* __restrict__ shift,
        const float* __restrict__ dw, const float* __restrict__ db) {
  int b = blockIdx.x, t = threadIdx.x;
  __shared__ __align__(16) unsigned short xh[240*CIP];
  __shared__ __align__(16) unsigned short xl[240*CIP];
  float* Ab = A + (size_t)b*CC*HW;
  for (int i = t; i < 15*CIP; i += 512) { xh[225*CIP + i] = 0; xl[225*CIP + i] = 0; }
  for (int i = t; i < CC*HW; i += 512) {
    int ci = i / HW, p = i - ci*HW;
    float v = Ab[i]*scale[ci] + shift[ci];
    __hip_bfloat16 h = __float2bfloat16(v);
    xh[p*CIP + ci] = *(unsigned short*)&h;
    xl[p*CIP + ci] = f2bf(v - __bfloat162float(h));
  }
  __syncthreads();
  int w = t >> 6, l = t & 63, g = l >> 4, n = l & 15;
  const short8* whp = (const short8*)Whi;
  const short8* wlp = (const short8*)Wlo;
  for (int nt = w; nt < 15; nt += 8) {
    short8 bh[4], bl[4];
    #pragma unroll
    for (int cs = 0; cs < 4; ++cs) {
      bh[cs] = *(const short8*)&xh[(nt*16 + n)*CIP + cs*32 + g*8];
      bl[cs] = *(const short8*)&xl[(nt*16 + n)*CIP + cs*32 + g*8];
    }
    f32x4 acc[8] = {};
    #pragma unroll
    for (int cs = 0; cs < 4; ++cs) {
      #pragma unroll
      for (int ct = 0; ct < 8; ++ct) {
        short8 ah = whp[(cs*8 + ct)*64 + l];
        short8 al = wlp[(cs*8 + ct)*64 + l];
        acc[ct] = __builtin_amdgcn_mfma_f32_16x16x32_bf16(ah, bh[cs], acc[ct], 0, 0, 0);
        acc[ct] = __builtin_amdgcn_mfma_f32_16x16x32_bf16(ah, bl[cs], acc[ct], 0, 0, 0);
        acc[ct] = __builtin_amdgcn_mfma_f32_16x16x32_bf16(al, bh[cs], acc[ct], 0, 0, 0);
      }
    }
    int p = nt*16 + n;
    if (p < HW) {
      #pragma unroll
      for (int ct = 0; ct < 8; ++ct) {
        #pragma unroll
        for (int r = 0; r < 4; ++r) {
          int co = ct*16 + g*4 + r;
          float y = acc[ct][r];
          y = (y >= 0.f) ? y : 0.01f*y;
          if (MODE == 1) { y = y*dw[co] + db[co]; y = fmaxf(y, 0.f); }
          Ab[co*HW + p] = y;
        }
      }
    }
  }
}

// ---------- depthwise 3x3 pad1 + bias + relu, grid (B, 8 ch-groups) ----------
__global__ __launch_bounds__(256) void k_dw3(float* __restrict__ A, const float* __restrict__ w,
                      const float* __restrict__ db) {
  int b = blockIdx.x, cg = blockIdx.y, t = threadIdx.x;
  __shared__ float xin[16][HW];
  float* Ab = A + ((size_t)b*CC + cg*16)*HW;
  for (int i = t; i < 16*HW; i += 256) xin[i/HW][i%HW] = Ab[i];
  __syncthreads();
  if (t < HW) {
    int y = t/15, x = t - y*15;
    for (int c = 0; c < 16; ++c) {
      int ch = cg*16 + c;
      float acc = db[ch];
      #pragma unroll
      for (int ky = 0; ky < 3; ++ky) {
        int iy = y + ky - 1;
        if (iy < 0 || iy >= 15) continue;
        #pragma unroll
        for (int kx = 0; kx < 3; ++kx) {
          int ix = x + kx - 1;
          if (ix < 0 || ix >= 15) continue;
          acc += w[ch*9 + ky*3 + kx]*xin[c][iy*15 + ix];
        }
      }
      Ab[c*HW + t] = fmaxf(acc, 0.f);
    }
  }
}

// ---------- attention 2 via MFMA: K proj folded into e2, V proj + residual ----------
__global__ __launch_bounds__(256) void k_attn2_mfma(float* __restrict__ A,
        const float* __restrict__ Wq,            // qkv_W base (Q rows 0..127)
        const unsigned short* __restrict__ Wk, const unsigned short* __restrict__ Wv) {
  int b = blockIdx.x, t = threadIdx.x;
  __shared__ __align__(16) unsigned short xh[240*CIP];
  __shared__ float att[240];
  __shared__ float cent[CC];
  __shared__ float red[256];
  float* Ab = A + (size_t)b*CC*HW;
  for (int i = t; i < 15*CIP; i += 256) xh[225*CIP + i] = 0;
  for (int i = t; i < CC*HW; i += 256) {
    int ci = i / HW, p = i - ci*HW;
    xh[p*CIP + ci] = f2bf(Ab[i]);
  }
  __syncthreads();
  if (t < CC) {
    const float* wq = Wq + (size_t)t*CC;
    float acc = 0.f;
    for (int ci = 0; ci < CC; ++ci) acc += wq[ci]*bf2f(xh[112*CIP + ci]);
    cent[t] = acc;
  }
  __syncthreads();
  int w = t >> 6, l = t & 63, g = l >> 4, n = l & 15;
  const short8* wkp = (const short8*)Wk;
  const short8* wvp = (const short8*)Wv;
  // e2 phase
  for (int nt = w; nt < 15; nt += 4) {
    int p = nt*16 + n;
    short8 bfr[4];
    #pragma unroll
    for (int cs = 0; cs < 4; ++cs)
      bfr[cs] = *(const short8*)&xh[(nt*16 + n)*CIP + cs*32 + g*8];
    float e2p = 0.f;
    #pragma unroll
    for (int ct = 0; ct < 8; ++ct) {
      f32x4 k = {};
      #pragma unroll
      for (int cs = 0; cs < 4; ++cs)
        k = __builtin_amdgcn_mfma_f32_16x16x32_bf16(wkp[(cs*8 + ct)*64 + l], bfr[cs], k, 0, 0, 0);
      #pragma unroll
      for (int r = 0; r < 4; ++r) { float d = cent[ct*16 + g*4 + r] - k[r]; e2p += d*d; }
    }
    e2p += __shfl_xor(e2p, 16);
    e2p += __shfl_xor(e2p, 32);
    if (g == 0 && p < HW) att[p] = 1.f/(1.f + sqrtf(e2p));
  }
  __syncthreads();
  // softmax over pixels
  {
    float val = (t < HW) ? att[t] : -1e30f;
    float m = block_reduce_max(val, red, t);
    float e = (t < HW) ? expf(val - m) : 0.f;
    float s = block_reduce_sum(e, red, t);
    if (t < 240) att[t] = (t < HW) ? e/s : 0.f;
  }
  __syncthreads();
  // V phase + residual (in-place, one element per lane)
  for (int nt = w; nt < 15; nt += 4) {
    int p = nt*16 + n;
    short8 bfr[4];
    #pragma unroll
    for (int cs = 0; cs < 4; ++cs)
      bfr[cs] = *(const short8*)&xh[(nt*16 + n)*CIP + cs*32 + g*8];
    float ap = att[p];
    #pragma unroll
    for (int ct = 0; ct < 8; ++ct) {
      f32x4 v = {};
      #pragma unroll
      for (int cs = 0; cs < 4; ++cs)
        v = __builtin_amdgcn_mfma_f32_16x16x32_bf16(wvp[(cs*8 + ct)*64 + l], bfr[cs], v, 0, 0, 0);
      if (p < HW) {
        #pragma unroll
        for (int r = 0; r < 4; ++r) {
          int co = ct*16 + g*4 + r;
          Ab[co*HW + p] = ap*v[r] + Ab[co*HW + p];
        }
      }
    }
  }
}

// ---------- BN3 + channel-attention gate via MFMA: reads A, writes D ----------
__global__ __launch_bounds__(512) void k_chatt_mfma(const float* __restrict__ A, float* __restrict__ D,
        const float* __restrict__ sc, const float* __restrict__ sh,
        const unsigned short* __restrict__ Wc1, const float* __restrict__ b1,
        const unsigned short* __restrict__ Wc2, const float* __restrict__ b2) {
  int b = blockIdx.x, t = threadIdx.x;
  __shared__ __align__(16) unsigned short xh[240*CIP];
  __shared__ __align__(16) unsigned short hb[240*CIPH];
  const float* Ab = A + (size_t)b*CC*HW;
  float* Db = D + (size_t)b*CC*HW;
  for (int i = t; i < 15*CIP; i += 512) xh[225*CIP + i] = 0;
  for (int i = t; i < 15*CIPH; i += 512) hb[225*CIPH + i] = 0;
  for (int i = t; i < CC*HW; i += 512) {
    int ci = i / HW, p = i - ci*HW;
    xh[p*CIP + ci] = f2bf(Ab[i]*sc[ci] + sh[ci]);
  }
  __syncthreads();
  int w = t >> 6, l = t & 63, g = l >> 4, n = l & 15;
  const short8* w1p = (const short8*)Wc1;
  const short8* w2p = (const short8*)Wc2;
  for (int nt = w; nt < 15; nt += 8) {
    int p = nt*16 + n;
    short8 bfr[4];
    #pragma unroll
    for (int cs = 0; cs < 4; ++cs)
      bfr[cs] = *(const short8*)&xh[(nt*16 + n)*CIP + cs*32 + g*8];
    #pragma unroll
    for (int ct = 0; ct < 2; ++ct) {
      f32x4 a = {};
      #pragma unroll
      for (int cs = 0; cs < 4; ++cs)
        a = __builtin_amdgcn_mfma_f32_16x16x32_bf16(w1p[(cs*2 + ct)*64 + l], bfr[cs], a, 0, 0, 0);
      if (p < HW) {
        #pragma unroll
        for (int r = 0; r < 4; ++r) {
          int co = ct*16 + g*4 + r;
          hb[p*CIPH + co] = f2bf(fmaxf(a[r] + b1[co], 0.f));
        }
      }
    }
  }
  __syncthreads();
  for (int nt = w; nt < 15; nt += 8) {
    int p = nt*16 + n;
    short8 bh = *(const short8*)&hb[(nt*16 + n)*CIPH + g*8];
    #pragma unroll
    for (int ct = 0; ct < 8; ++ct) {
      f32x4 a = {};
      a = __builtin_amdgcn_mfma_f32_16x16x32_bf16(w2p[ct*64 + l], bh, a, 0, 0, 0);
      if (p < HW) {
        #pragma unroll
        for (int r = 0; r < 4; ++r) {
          int co = ct*16 + g*4 + r;
          float s = a[r] + b2[co];
          float gt = 1.f/(1.f + expf(-s));
          Db[co*HW + p] = (Ab[co*HW + p]*sc[co] + sh[co])*gt;
        }
      }
    }
  }
}

// ---------- 7x7 conv 128->32 (MFMA, from round 2) ----------
#define CIP_A 136
__global__ __launch_bounds__(512) void k_conv7a_mfma(const float* __restrict__ D,
        const unsigned short* __restrict__ Wa, float* __restrict__ S) {
  int b = blockIdx.x, t = threadIdx.x;
  __shared__ __align__(16) unsigned short xb[21*22*CIP_A];
  unsigned int* xw = (unsigned int*)xb;
  for (int i = t; i < 21*22*CIP_A/2; i += 512) xw[i] = 0u;
  __syncthreads();
  const float* Db = D + (size_t)b*CC*HW;
  for (int i = t; i < CC*HW; i += 512) {
    int ci = i / HW, p = i - ci*HW;
    int y = p/15, x = p - y*15;
    xb[((y+3)*22 + (x+3))*CIP_A + ci] = f2bf(Db[i]);
  }
  __syncthreads();
  int w = t >> 6, l = t & 63;
  int g = l >> 4, x = l & 15;
  int nt0 = w, nt1 = w + 8;
  f32x4 acc[2][2] = {};
  const short8* wp = (const short8*)Wa;
  for (int s = 0; s < 49; ++s) {
    int dy = s / 7, dx = s % 7;
    for (int cs = 0; cs < 4; ++cs) {
      short8 a0 = wp[((s*4 + cs)*2 + 0)*64 + l];
      short8 a1 = wp[((s*4 + cs)*2 + 1)*64 + l];
      short8 b0 = *(const short8*)&xb[((nt0+dy)*22 + (x+dx))*CIP_A + cs*32 + g*8];
      acc[0][0] = __builtin_amdgcn_mfma_f32_16x16x32_bf16(a0, b0, acc[0][0], 0, 0, 0);
      acc[1][0] = __builtin_amdgcn_mfma_f32_16x16x32_bf16(a1, b0, acc[1][0], 0, 0, 0);
      if (nt1 < 15) {
        short8 b1 = *(const short8*)&xb[((nt1+dy)*22 + (x+dx))*CIP_A + cs*32 + g*8];
        acc[0][1] = __builtin_amdgcn_mfma_f32_16x16x32_bf16(a0, b1, acc[0][1], 0, 0, 0);
        acc[1][1] = __builtin_amdgcn_mfma_f32_16x16x32_bf16(a1, b1, acc[1][1], 0, 0, 0);
      }
    }
  }
  if (x < 15) {
    for (int ct = 0; ct < 2; ++ct)
      for (int ni = 0; ni < 2; ++ni) {
        int nt = ni ? nt1 : nt0;
        if (nt >= 15) continue;
        float* out = S + ((size_t)b*32 + ct*16 + g*4)*HW + nt*15 + x;
        #pragma unroll
        for (int r = 0; r < 4; ++r) out[r*HW] = acc[ct][ni][r];
      }
  }
}

// ---------- 7x7 conv 32->128, BN+relu at staging (MFMA, from round 2) ----------
#define CIP_B 40
__global__ __launch_bounds__(512) void k_conv7b_mfma(const float* __restrict__ S,
        const float* __restrict__ sc, const float* __restrict__ sh,
        const unsigned short* __restrict__ Wb, float* __restrict__ O) {
  int b = blockIdx.x, t = threadIdx.x;
  __shared__ __align__(16) unsigned short xb[21*22*CIP_B];
  unsigned int* xw = (unsigned int*)xb;
  for (int i = t; i < 21*22*CIP_B/2; i += 512) xw[i] = 0u;
  __syncthreads();
  const float* Sb = S + (size_t)b*32*HW;
  for (int i = t; i < 32*HW; i += 512) {
    int ci = i / HW, p = i - ci*HW;
    int y = p/15, xx = p - y*15;
    float v = fmaxf(Sb[i]*sc[ci] + sh[ci], 0.f);
    xb[((y+3)*22 + (xx+3))*CIP_B + ci] = f2bf(v);
  }
  __syncthreads();
  int w = t >> 6, l = t & 63;
  int g = l >> 4, x = l & 15;
  int nt0 = w, nt1 = w + 8;
  f32x4 acc[8][2] = {};
  const short8* wp = (const short8*)Wb;
  for (int s = 0; s < 49; ++s) {
    int dy = s / 7, dx = s % 7;
    short8 b0 = *(const short8*)&xb[((nt0+dy)*22 + (x+dx))*CIP_B + g*8];
    short8 b1 = b0;
    if (nt1 < 15) b1 = *(const short8*)&xb[((nt1+dy)*22 + (x+dx))*CIP_B + g*8];
    #pragma unroll
    for (int ct = 0; ct < 8; ++ct) {
      short8 a = wp[(s*8 + ct)*64 + l];
      acc[ct][0] = __builtin_amdgcn_mfma_f32_16x16x32_bf16(a, b0, acc[ct][0], 0, 0, 0);
      if (nt1 < 15) acc[ct][1] = __builtin_amdgcn_mfma_f32_16x16x32_bf16(a, b1, acc[ct][1], 0, 0, 0);
    }
  }
  if (x < 15) {
    for (int ct = 0; ct < 8; ++ct)
      for (int ni = 0; ni < 2; ++ni) {
        int nt = ni ? nt1 : nt0;
        if (nt >= 15) continue;
        float* out = O + ((size_t)b*CC + ct*16 + g*4)*HW + nt*15 + x;
        #pragma unroll
        for (int r = 0; r < 4; ++r) out[r*HW] = acc[ct][ni][r];
      }
  }
}

// ---------- final: D *= sigmoid(bn5(A)) ----------
__global__ __launch_bounds__(256) void k_final(float* __restrict__ D, const float* __restrict__ A,
                        const float* __restrict__ sc, const float* __restrict__ sh) {
  size_t i = (size_t)blockIdx.x*256 + threadIdx.x;
  int c = (int)((i / HW) % CC);
  float s = A[i]*sc[c] + sh[c];
  D[i] *= 1.f/(1.f + expf(-s));
}

extern "C" void kernel_launch(void* const* d_in, const int* in_sizes, int n_in,
                              void* d_out, int out_size, void* d_ws, size_t ws_size,
                              hipStream_t stream) {
  (void)in_sizes; (void)n_in; (void)out_size; (void)ws_size;
  const float* x1    = (const float*)d_in[0];
  const float* x2    = (const float*)d_in[1];
  const float* lam   = (const float*)d_in[2];
  const float* bn1_g = (const float*)d_in[3];
  const float* bn1_b = (const float*)d_in[4];
  const float* pW1   = (const float*)d_in[5];
  const float* dW1   = (const float*)d_in[6];
  const float* db1   = (const float*)d_in[7];
  const float* bn2_g = (const float*)d_in[8];
  const float* bn2_b = (const float*)d_in[9];
  const float* pW2   = (const float*)d_in[10];
  const float* dW2   = (const float*)d_in[11];
  const float* db2   = (const float*)d_in[12];
  const float* qkvW  = (const float*)d_in[13];
  const float* bn3_g = (const float*)d_in[14];
  const float* bn3_b = (const float*)d_in[15];
  const float* ca_w1 = (const float*)d_in[16];
  const float* ca_b1 = (const float*)d_in[17];
  const float* ca_w2 = (const float*)d_in[18];
  const float* ca_b2 = (const float*)d_in[19];
  const float* sa_w1 = (const float*)d_in[20];
  const float* sbn1_g= (const float*)d_in[22];
  const float* sbn1_b= (const float*)d_in[23];
  const float* sa_w2 = (const float*)d_in[24];
  const float* sbn2_g= (const float*)d_in[26];
  const float* sbn2_b= (const float*)d_in[27];

  float* D = (float*)d_out;
  float* A = (float*)d_ws;                          // (512,128,225) f32
  float* S = A + (size_t)BB*CC*HW;                  // (512,32,225)  f32
  float* part = S + (size_t)BB*32*HW;               // 4096 f32
  float* st = part + 4096;                          // 1280 f32 stats
  float *sc1 = st,      *sh1 = st+128,  *sc2 = st+256, *sh2 = st+384,
        *sc3 = st+512,  *sh3 = st+640,  *sc4 = st+768, *sh4 = st+800,
        *sc5 = st+832,  *sh5 = st+960;
  unsigned short* Wa  = (unsigned short*)(st + 1280);  // 49*4096
  unsigned short* Wb  = Wa + 49*4096;                  // 49*4096
  unsigned short* W1h = Wb + 49*4096;                  // 16384 each below
  unsigned short* W1l = W1h + 16384;
  unsigned short* W2h = W1l + 16384;
  unsigned short* W2l = W2h + 16384;
  unsigned short* Wk  = W2l + 16384;
  unsigned short* Wv  = Wk  + 16384;
  unsigned short* Wc1 = Wv  + 16384;                   // 4096
  unsigned short* Wc2 = Wc1 + 4096;                    // 4096

  k_prep_wa <<<784, 256, 0, stream>>>(sa_w1, Wa);
  k_prep_wb <<<784, 256, 0, stream>>>(sa_w2, Wb);
  k_prep_pw <<<64, 256, 0, stream>>>(pW1, W1h, W1l);
  k_prep_pw <<<64, 256, 0, stream>>>(pW2, W2h, W2l);
  k_prep_kv <<<64, 256, 0, stream>>>(qkvW, Wk, Wv);
  k_prep_ca1<<<16, 256, 0, stream>>>(ca_w1, Wc1);
  k_prep_ca2<<<16, 256, 0, stream>>>(ca_w2, Wc2);

  k_attn1 <<<BB, 256, 0, stream>>>(x1, x2, lam, A);
  k_bnstats2<<<dim3(CC,16), 256, 0, stream>>>(A, CC, part);
  k_bnfin <<<1, CC, 0, stream>>>(part, CC, bn1_g, bn1_b, sc1, sh1);
  k_pw_mfma<1><<<BB, 512, 0, stream>>>(A, W1h, W1l, sc1, sh1, dW1, db1);
  k_bnstats2<<<dim3(CC,16), 256, 0, stream>>>(A, CC, part);
  k_bnfin <<<1, CC, 0, stream>>>(part, CC, bn2_g, bn2_b, sc2, sh2);
  k_pw_mfma<2><<<BB, 512, 0, stream>>>(A, W2h, W2l, sc2, sh2, nullptr, nullptr);
  k_dw3   <<<dim3(BB,8), 256, 0, stream>>>(A, dW2, db2);
  k_attn2_mfma<<<BB, 256, 0, stream>>>(A, qkvW, Wk, Wv);
  k_bnstats2<<<dim3(CC,16), 256, 0, stream>>>(A, CC, part);
  k_bnfin <<<1, CC, 0, stream>>>(part, CC, bn3_g, bn3_b, sc3, sh3);
  k_chatt_mfma<<<BB, 512, 0, stream>>>(A, D, sc3, sh3, Wc1, ca_b1, Wc2, ca_b2);
  k_conv7a_mfma<<<BB, 512, 0, stream>>>(D, Wa, S);
  k_bnstats2<<<dim3(32,16), 256, 0, stream>>>(S, 32, part);
  k_bnfin <<<1, 32, 0, stream>>>(part, 32, sbn1_g, sbn1_b, sc4, sh4);
  k_conv7b_mfma<<<BB, 512, 0, stream>>>(S, sc4, sh4, Wb, A);
  k_bnstats2<<<dim3(CC,16), 256, 0, stream>>>(A, CC, part);
  k_bnfin <<<1, CC, 0, stream>>>(part, CC, sbn2_g, sbn2_b, sc5, sh5);
  k_final <<<(BB*CC*HW)/256, 256, 0, stream>>>(D, A, sc5, sh5);
}